// Round 4
// baseline (106.345 us; speedup 1.0000x reference)
//
#include <hip/hip_runtime.h>
#include <math.h>

#define N       4096
#define NPARAM  15
#define BI      256        // i-rows per pairwise block (one per thread)
#define NJP     128        // j-slices, partial-sum path (8 blocks/CU -> full occupancy)
#define NJA     16         // j-slices, atomic fallback path

__device__ __forceinline__ void derive_params(const float* __restrict__ r, float* o) {
  // r -> (t, ra, dec, psi, mc, f_isco, dist, 0)
  float m1 = r[0] * 95.0f + 5.0f;
  float m2 = r[1] * 95.0f + 5.0f;
  float msum = m1 + m2;
  float mc = expf(0.6f * logf(m1 * m2) - 0.2f * logf(msum));
  o[0] = r[5];
  o[1] = r[3];
  o[2] = r[4];
  o[3] = r[7];
  o[4] = mc;
  o[5] = 220.0f / msum;
  o[6] = r[2] * 2950.0f + 50.0f;
  o[7] = 0.0f;
}

// BJ = j's per slice; PARTIAL: true -> store partial sums to out[jb][i][8],
// false -> atomicAdd into out[i][8] (fallback when ws is too small).
template <int BJ, bool PARTIAL>
__global__ __launch_bounds__(256) void pairwise_kernel(
    const float* __restrict__ p, float* __restrict__ out) {
  __shared__ float sh[BJ * 8];
  int ib = blockIdx.x;
  int jb = blockIdx.y;
  int t  = threadIdx.x;
  int i  = ib * BI + t;

  if (t < BJ) {
    int j = jb * BJ + t;
    float o[8];
    derive_params(p + (size_t)j * NPARAM, o);
    float4* dst = (float4*)(sh + t * 8);
    dst[0] = make_float4(o[0], o[1], o[2], o[3]);
    dst[1] = make_float4(o[4], o[5], o[6], o[7]);
  }

  float pi[8];
  derive_params(p + (size_t)i * NPARAM, pi);
  float ti = pi[0], rai = pi[1], deci = pi[2], psii = pi[3];
  float mci = pi[4], fi = pi[5], di = pi[6];

  __syncthreads();

  float s0 = 0.f, s1 = 0.f, s2 = 0.f, s3 = 0.f,
        s4 = 0.f, s5 = 0.f, s6 = 0.f, s7 = 0.f;

#pragma unroll 8
  for (int j = 0; j < BJ; j++) {
    float4 a0 = ((const float4*)sh)[j * 2];       // t, ra, dec, psi
    float4 a1 = ((const float4*)sh)[j * 2 + 1];   // mc, f, dist, pad
    float dt   = ti - a0.x;
    float dra  = rai - a0.y;
    float ddec = deci - a0.z;
    float dpsi = psii - a0.w;
    s0 += fabsf(dt);
    s1 += sqrtf(dra * dra + ddec * ddec);
    float dmc = mci - a1.x;
    s2 += 30.0f * __builtin_amdgcn_rcpf(30.0f + fabsf(dmc));
    float df = fi - a1.y;
    s3 += __expf(-0.01f * fabsf(df));
    float lo = fminf(di, a1.z);
    float hi = fmaxf(di, a1.z);
    s4 += lo * __builtin_amdgcn_rcpf(hi);
    s5 += fabsf(dpsi);
    s6 += fabsf(dra);
    s7 += fabsf(ddec);
  }

  if (PARTIAL) {
    float* xi = out + ((size_t)jb * N + i) * 8;
    ((float4*)xi)[0] = make_float4(s0, s1, s2, s3);
    ((float4*)xi)[1] = make_float4(s4, s5, s6, s7);
  } else {
    float* xi = out + (size_t)i * 8;
    atomicAdd(xi + 0, s0); atomicAdd(xi + 1, s1);
    atomicAdd(xi + 2, s2); atomicAdd(xi + 3, s3);
    atomicAdd(xi + 4, s4); atomicAdd(xi + 5, s5);
    atomicAdd(xi + 6, s6); atomicAdd(xi + 7, s7);
  }
}

// SLICES-way reduce (8 threads per row, coalesced) + fused tiny MLP.
// SLICES=1 reads X[i][8] directly (atomic-fallback layout).
template <int SLICES>
__global__ __launch_bounds__(256) void mlp_kernel(
    const float* __restrict__ X,
    const float* __restrict__ W1, const float* __restrict__ b1,
    const float* __restrict__ ln_g, const float* __restrict__ ln_b,
    const float* __restrict__ W2, const float* __restrict__ b2,
    float* __restrict__ out) {
  __shared__ float sW1[8 * 32], sW2[32 * 16];
  __shared__ float sb1[32], sg[32], sbb[32], sb2[16];
  __shared__ float sx[32 * 8];   // reduced features for this block's 32 rows
  int t = threadIdx.x;
  sW1[t] = W1[t];
  sW2[t] = W2[t];
  sW2[t + 256] = W2[t + 256];
  if (t < 32) { sb1[t] = b1[t]; sg[t] = ln_g[t]; sbb[t] = ln_b[t]; }
  if (t < 16) sb2[t] = b2[t];

  // reduction: 32 rows/block, 8 threads/row (one per feature)
  int i0 = blockIdx.x * 32;
  int r  = t >> 3;
  int f  = t & 7;
  {
    float s = 0.f;
    const float* src = X + (size_t)(i0 + r) * 8 + f;
#pragma unroll 8
    for (int jb = 0; jb < SLICES; jb++) s += src[(size_t)jb * N * 8];
    sx[r * 8 + f] = s;
  }
  __syncthreads();

  if (t < 32) {
    const float diag[8] = {0.f, 0.f, 1.f, 1.f, 1.f, 0.f, 0.f, 0.f};
    const float inv_nm1 = 1.0f / (float)(N - 1);
    float x[8];
#pragma unroll
    for (int k = 0; k < 8; k++) x[k] = (sx[t * 8 + k] - diag[k]) * inv_nm1;

    float h[32];
#pragma unroll
    for (int o = 0; o < 32; o++) {
      float a = sb1[o];
#pragma unroll
      for (int k = 0; k < 8; k++) a += x[k] * sW1[k * 32 + o];
      h[o] = a;
    }

    float mu = 0.f;
#pragma unroll
    for (int o = 0; o < 32; o++) mu += h[o];
    mu *= (1.0f / 32.0f);
    float var = 0.f;
#pragma unroll
    for (int o = 0; o < 32; o++) { float d = h[o] - mu; var += d * d; }
    var *= (1.0f / 32.0f);
    float inv = rsqrtf(var + 1e-5f);

#pragma unroll
    for (int o = 0; o < 32; o++) {
      float hn = (h[o] - mu) * inv * sg[o] + sbb[o];
      h[o] = 0.5f * hn * (1.0f + erff(hn * 0.70710678118654752f));
    }

    int row = i0 + t;
    float4* oi = (float4*)(out + (size_t)row * 16);
#pragma unroll
    for (int q = 0; q < 4; q++) {
      float a0 = sb2[q * 4 + 0], a1 = sb2[q * 4 + 1],
            a2 = sb2[q * 4 + 2], a3 = sb2[q * 4 + 3];
#pragma unroll
      for (int k = 0; k < 32; k++) {
        float hk = h[k];
        a0 += hk * sW2[k * 16 + q * 4 + 0];
        a1 += hk * sW2[k * 16 + q * 4 + 1];
        a2 += hk * sW2[k * 16 + q * 4 + 2];
        a3 += hk * sW2[k * 16 + q * 4 + 3];
      }
      oi[q] = make_float4(a0, a1, a2, a3);
    }
  }
}

extern "C" void kernel_launch(void* const* d_in, const int* in_sizes, int n_in,
                              void* d_out, int out_size, void* d_ws, size_t ws_size,
                              hipStream_t stream) {
  const float* p    = (const float*)d_in[0];
  const float* W1   = (const float*)d_in[1];
  const float* b1   = (const float*)d_in[2];
  const float* ln_g = (const float*)d_in[3];
  const float* ln_b = (const float*)d_in[4];
  const float* W2   = (const float*)d_in[5];
  const float* b2   = (const float*)d_in[6];
  float* out = (float*)d_out;
  float* ws  = (float*)d_ws;

  const size_t need_partial = (size_t)NJP * N * 8 * sizeof(float);  // 16 MB
  if (ws_size >= need_partial) {
    // split-K with private partial buffers; no atomics, no memset needed
    dim3 grid(N / BI, NJP);
    pairwise_kernel<N / NJP, true><<<grid, 256, 0, stream>>>(p, ws);
    mlp_kernel<NJP><<<N / 32, 256, 0, stream>>>(ws, W1, b1, ln_g, ln_b, W2, b2, out);
  } else {
    // fallback: atomic accumulation (low contention, 16 slices)
    hipMemsetAsync(ws, 0, (size_t)N * 8 * sizeof(float), stream);
    dim3 grid(N / BI, NJA);
    pairwise_kernel<N / NJA, false><<<grid, 256, 0, stream>>>(p, ws);
    mlp_kernel<1><<<N / 32, 256, 0, stream>>>(ws, W1, b1, ln_g, ln_b, W2, b2, out);
  }
}

// Round 5
// 89.607 us; speedup vs baseline: 1.1868x; 1.1868x over previous
//
#include <hip/hip_runtime.h>
#include <math.h>

#define N       4096
#define NPARAM  15
#define NJ      32          // j-slices (partial-sum path)
#define IB      64          // i-rows per pairwise block (one per lane)
#define JPB     (N / NJ)    // 128 j's per block
#define JPW     (JPB / 4)   // 32 j's per wave

__device__ __forceinline__ void derive_params(const float* __restrict__ r, float* o) {
  // r -> (t, ra, dec, psi, mc, f_isco, dist, 0)
  float m1 = r[0] * 95.0f + 5.0f;
  float m2 = r[1] * 95.0f + 5.0f;
  float msum = m1 + m2;
  float mc = expf(0.6f * logf(m1 * m2) - 0.2f * logf(msum));
  o[0] = r[5];
  o[1] = r[3];
  o[2] = r[4];
  o[3] = r[7];
  o[4] = mc;
  o[5] = 220.0f / msum;
  o[6] = r[2] * 2950.0f + 50.0f;
  o[7] = 0.0f;
}

// Block: 64 i's (one per lane), 4 waves split 128 j's (32 each), LDS-reduce,
// then one coalesced store of 64x8 partials to out[jb][i][8] (PARTIAL) or
// atomicAdd into out[i][8] (fallback).
template <bool PARTIAL>
__global__ __launch_bounds__(256, 8) void pairwise_kernel(
    const float* __restrict__ p, float* __restrict__ out) {
  __shared__ float shj[JPB * 8];        // 128 j-points x 8 = 4 KB
  __shared__ float sacc[4 * IB * 8];    // 4 waves x 64 i x 8 = 8 KB
  int t    = threadIdx.x;
  int ib   = blockIdx.x;
  int jb   = blockIdx.y;
  int w    = t >> 6;
  int lane = t & 63;
  int i    = ib * IB + lane;

  // stage this block's 128 j-points (threads 0..127 derive one each)
  if (t < JPB) {
    int j = jb * JPB + t;
    float o[8];
    derive_params(p + (size_t)j * NPARAM, o);
    float4* dst = (float4*)(shj + t * 8);
    dst[0] = make_float4(o[0], o[1], o[2], o[3]);
    dst[1] = make_float4(o[4], o[5], o[6], o[7]);
  }

  // my i-point (same 64 i's derived by all 4 waves; negligible redundancy)
  float pi[8];
  derive_params(p + (size_t)i * NPARAM, pi);
  float ti = pi[0], rai = pi[1], deci = pi[2], psii = pi[3];
  float mci = pi[4], fi = pi[5], di = pi[6];

  __syncthreads();

  float s0 = 0.f, s1 = 0.f, s2 = 0.f, s3 = 0.f,
        s4 = 0.f, s5 = 0.f, s6 = 0.f, s7 = 0.f;

  // wave w handles j in [w*JPW, (w+1)*JPW) — LDS reads are wave-uniform (broadcast)
  const float4* jbase = (const float4*)shj + (size_t)w * JPW * 2;
#pragma unroll 8
  for (int j = 0; j < JPW; j++) {
    float4 a0 = jbase[j * 2];       // t, ra, dec, psi
    float4 a1 = jbase[j * 2 + 1];   // mc, f, dist, pad
    float dt   = ti - a0.x;
    float dra  = rai - a0.y;
    float ddec = deci - a0.z;
    float dpsi = psii - a0.w;
    s0 += fabsf(dt);
    s1 += sqrtf(dra * dra + ddec * ddec);
    float dmc = mci - a1.x;
    s2 += 30.0f * __builtin_amdgcn_rcpf(30.0f + fabsf(dmc));
    float df = fi - a1.y;
    s3 += __expf(-0.01f * fabsf(df));
    float lo = fminf(di, a1.z);
    float hi = fmaxf(di, a1.z);
    s4 += lo * __builtin_amdgcn_rcpf(hi);
    s5 += fabsf(dpsi);
    s6 += fabsf(dra);
    s7 += fabsf(ddec);
  }

  // per-wave partials -> LDS
  float4* d = (float4*)(sacc + ((size_t)w * IB + lane) * 8);
  d[0] = make_float4(s0, s1, s2, s3);
  d[1] = make_float4(s4, s5, s6, s7);
  __syncthreads();

  // 4-way reduce + store: 512 (i,feat) values by 256 threads, coalesced
#pragma unroll
  for (int k = 0; k < 2; k++) {
    int pidx = t + k * 256;
    float v = sacc[pidx] + sacc[512 + pidx] + sacc[1024 + pidx] + sacc[1536 + pidx];
    if (PARTIAL) {
      out[((size_t)jb * N + (size_t)ib * IB) * 8 + pidx] = v;
    } else {
      atomicAdd(&out[((size_t)ib * IB) * 8 + pidx], v);
    }
  }
}

// Fused SLICES-way reduce + tiny MLP. 16 rows/block; reduction by 2 threads x 8
// feats per row; MLP by 16 threads per row (2 hidden units each, shfl LN).
template <int SLICES>
__global__ __launch_bounds__(256) void mlp_kernel(
    const float* __restrict__ X,
    const float* __restrict__ W1, const float* __restrict__ b1,
    const float* __restrict__ ln_g, const float* __restrict__ ln_b,
    const float* __restrict__ W2, const float* __restrict__ b2,
    float* __restrict__ out) {
  __shared__ float sW1[8 * 32], sW2[32 * 16];
  __shared__ float sb1[32], sg[32], sbb[32], sb2[16];
  __shared__ float sx[16 * 8];     // reduced features per row
  __shared__ float sh[16 * 32];    // post-GELU hidden per row
  __shared__ float stmp[256];
  int t = threadIdx.x;
  sW1[t] = W1[t];
  sW2[t] = W2[t];
  sW2[t + 256] = W2[t + 256];
  if (t < 32) { sb1[t] = b1[t]; sg[t] = ln_g[t]; sbb[t] = ln_b[t]; }
  if (t < 16) sb2[t] = b2[t];

  int i0 = blockIdx.x * 16;

  // ---- reduce partial[SLICES][N][8] over slices ----
  {
    int r = t >> 4;          // row 0..15
    int q = (t >> 3) & 1;    // slice-half
    int f = t & 7;           // feature
    float s = 0.f;
    if (SLICES == 1) {
      if (q == 0) s = X[(size_t)(i0 + r) * 8 + f];
    } else {
      const float* src = X + ((size_t)(q * (SLICES / 2)) * N + (i0 + r)) * 8 + f;
#pragma unroll
      for (int k = 0; k < SLICES / 2; k++) s += src[(size_t)k * N * 8];
    }
    stmp[t] = s;
    __syncthreads();
    if (q == 0) sx[r * 8 + f] = stmp[t] + stmp[t + 8];
  }
  __syncthreads();

  // ---- MLP: 16 threads per row ----
  {
    int r = t >> 4;          // row 0..15 (4 rows per wave, 16-lane groups)
    int u = t & 15;
    const float diag[8] = {0.f, 0.f, 1.f, 1.f, 1.f, 0.f, 0.f, 0.f};
    const float inv_nm1 = 1.0f / (float)(N - 1);
    float x[8];
#pragma unroll
    for (int k = 0; k < 8; k++) x[k] = (sx[r * 8 + k] - diag[k]) * inv_nm1;

    int o0 = u * 2, o1 = o0 + 1;
    float h0 = sb1[o0], h1 = sb1[o1];
#pragma unroll
    for (int k = 0; k < 8; k++) {
      h0 += x[k] * sW1[k * 32 + o0];
      h1 += x[k] * sW1[k * 32 + o1];
    }

    // LayerNorm stats across the row's 32 hidden units (16-lane shfl groups)
    float sum = h0 + h1;
#pragma unroll
    for (int m = 1; m < 16; m <<= 1) sum += __shfl_xor(sum, m);
    float mu = sum * (1.0f / 32.0f);
    float d0 = h0 - mu, d1 = h1 - mu;
    float vs = d0 * d0 + d1 * d1;
#pragma unroll
    for (int m = 1; m < 16; m <<= 1) vs += __shfl_xor(vs, m);
    float inv = rsqrtf(vs * (1.0f / 32.0f) + 1e-5f);

    float hn0 = d0 * inv * sg[o0] + sbb[o0];
    float hn1 = d1 * inv * sg[o1] + sbb[o1];
    float g0 = 0.5f * hn0 * (1.0f + erff(hn0 * 0.70710678118654752f));
    float g1 = 0.5f * hn1 * (1.0f + erff(hn1 * 0.70710678118654752f));
    sh[r * 32 + o0] = g0;
    sh[r * 32 + o1] = g1;
    __syncthreads();

    // W2: each thread computes out[row][u]
    float a = sb2[u];
#pragma unroll
    for (int k = 0; k < 32; k++) a += sh[r * 32 + k] * sW2[k * 16 + u];
    out[(size_t)(i0 + r) * 16 + u] = a;
  }
}

extern "C" void kernel_launch(void* const* d_in, const int* in_sizes, int n_in,
                              void* d_out, int out_size, void* d_ws, size_t ws_size,
                              hipStream_t stream) {
  const float* p    = (const float*)d_in[0];
  const float* W1   = (const float*)d_in[1];
  const float* b1   = (const float*)d_in[2];
  const float* ln_g = (const float*)d_in[3];
  const float* ln_b = (const float*)d_in[4];
  const float* W2   = (const float*)d_in[5];
  const float* b2   = (const float*)d_in[6];
  float* out = (float*)d_out;
  float* ws  = (float*)d_ws;

  const size_t need_partial = (size_t)NJ * N * 8 * sizeof(float);  // 4 MB
  dim3 grid(N / IB, NJ);
  if (ws_size >= need_partial) {
    // split-K with private partial buffers; no atomics, no memset needed
    pairwise_kernel<true><<<grid, 256, 0, stream>>>(p, ws);
    mlp_kernel<NJ><<<N / 16, 256, 0, stream>>>(ws, W1, b1, ln_g, ln_b, W2, b2, out);
  } else {
    // fallback: atomic accumulation into X[N][8]
    hipMemsetAsync(ws, 0, (size_t)N * 8 * sizeof(float), stream);
    pairwise_kernel<false><<<grid, 256, 0, stream>>>(p, ws);
    mlp_kernel<1><<<N / 16, 256, 0, stream>>>(ws, W1, b1, ln_g, ln_b, W2, b2, out);
  }
}

// Round 6
// 83.155 us; speedup vs baseline: 1.2789x; 1.0776x over previous
//
#include <hip/hip_runtime.h>
#include <math.h>

#define N       4096
#define NPARAM  15
#define NJ      32          // j-slices (partial-sum path)
#define IB      64          // i-rows per pairwise block (one per lane)
#define JPB     (N / NJ)    // 128 j's per block
#define JPW     (JPB / 4)   // 32 j's per wave

// Derived per-point params (rescaled so the O(n^2) loop is minimal):
//   o0 = t, o1 = ra, o2 = dec, o3 = psi
//   o4 = mc/30                        (mass_sim = rcp(1+|d o4|))
//   o5 = 220*0.01*log2(e)/msum       (freq_ov  = exp2(-|d o5|))
//   o6 = log2(dist)                   (dist_rat = exp2(-|d o6|), exact)
__device__ __forceinline__ void derive_params(const float* __restrict__ r, float* o) {
  float m1 = fmaf(r[0], 95.0f, 5.0f);
  float m2 = fmaf(r[1], 95.0f, 5.0f);
  float msum = m1 + m2;
  // mc/30 = exp2(0.6*log2(m1*m2) - 0.2*log2(msum) - log2(30))
  float mc30 = __builtin_amdgcn_exp2f(
      0.6f * __builtin_amdgcn_logf(m1 * m2)
      - 0.2f * __builtin_amdgcn_logf(msum)
      - 4.906890595608519f);
  o[0] = r[5];
  o[1] = r[3];
  o[2] = r[4];
  o[3] = r[7];
  o[4] = mc30;
  o[5] = 3.1739290899556993f * __builtin_amdgcn_rcpf(msum);
  o[6] = __builtin_amdgcn_logf(fmaf(r[2], 2950.0f, 50.0f));
  o[7] = 0.0f;
}

// Block: 64 i's (one per lane), 4 waves split 128 j's (32 each), LDS-reduce,
// then one coalesced store of 64x8 partials to out[jb][i][8] (PARTIAL) or
// atomicAdd into out[i][8] (fallback).
template <bool PARTIAL>
__global__ __launch_bounds__(256, 8) void pairwise_kernel(
    const float* __restrict__ p, float* __restrict__ out) {
  __shared__ float shj[JPB * 8];        // 128 j-points x 8 = 4 KB
  __shared__ float sacc[4 * IB * 8];    // 4 waves x 64 i x 8 = 8 KB
  int t    = threadIdx.x;
  int ib   = blockIdx.x;
  int jb   = blockIdx.y;
  int w    = t >> 6;
  int lane = t & 63;
  int i    = ib * IB + lane;

  // stage this block's 128 j-points (threads 0..127 derive one each)
  if (t < JPB) {
    int j = jb * JPB + t;
    float o[8];
    derive_params(p + (size_t)j * NPARAM, o);
    float4* dst = (float4*)(shj + t * 8);
    dst[0] = make_float4(o[0], o[1], o[2], o[3]);
    dst[1] = make_float4(o[4], o[5], o[6], o[7]);
  }

  // my i-point (derived redundantly by each wave; amortized over 32 j's)
  float pi[8];
  derive_params(p + (size_t)i * NPARAM, pi);
  float ti = pi[0], rai = pi[1], deci = pi[2], psii = pi[3];
  float mci = pi[4], fi = pi[5], di = pi[6];

  __syncthreads();

  float s0 = 0.f, s1 = 0.f, s2 = 0.f, s3 = 0.f,
        s4 = 0.f, s5 = 0.f, s6 = 0.f, s7 = 0.f;

  // wave w handles j in [w*JPW, (w+1)*JPW) — LDS reads are wave-uniform (broadcast)
  const float4* jbase = (const float4*)shj + (size_t)w * JPW * 2;
#pragma unroll 16
  for (int j = 0; j < JPW; j++) {
    float4 a0 = jbase[j * 2];       // t, ra, dec, psi
    float4 a1 = jbase[j * 2 + 1];   // mc/30, f', log2(dist), pad
    float dra  = rai - a0.y;
    float ddec = deci - a0.z;
    s0 += fabsf(ti - a0.x);
    s5 += fabsf(psii - a0.w);
    s6 += fabsf(dra);
    s7 += fabsf(ddec);
    s1 += __builtin_amdgcn_sqrtf(fmaf(dra, dra, ddec * ddec));
    s2 += __builtin_amdgcn_rcpf(1.0f + fabsf(mci - a1.x));
    s3 += __builtin_amdgcn_exp2f(-fabsf(fi - a1.y));
    s4 += __builtin_amdgcn_exp2f(-fabsf(di - a1.z));
  }

  // per-wave partials -> LDS
  float4* d = (float4*)(sacc + ((size_t)w * IB + lane) * 8);
  d[0] = make_float4(s0, s1, s2, s3);
  d[1] = make_float4(s4, s5, s6, s7);
  __syncthreads();

  // 4-way reduce + store: 512 (i,feat) values by 256 threads, coalesced
#pragma unroll
  for (int k = 0; k < 2; k++) {
    int pidx = t + k * 256;
    float v = sacc[pidx] + sacc[512 + pidx] + sacc[1024 + pidx] + sacc[1536 + pidx];
    if (PARTIAL) {
      out[((size_t)jb * N + (size_t)ib * IB) * 8 + pidx] = v;
    } else {
      atomicAdd(&out[((size_t)ib * IB) * 8 + pidx], v);
    }
  }
}

// Fused SLICES-way reduce + tiny MLP. 16 rows/block; reduction by 2 threads x 8
// feats per row; MLP by 16 threads per row (2 hidden units each, shfl LN).
template <int SLICES>
__global__ __launch_bounds__(256) void mlp_kernel(
    const float* __restrict__ X,
    const float* __restrict__ W1, const float* __restrict__ b1,
    const float* __restrict__ ln_g, const float* __restrict__ ln_b,
    const float* __restrict__ W2, const float* __restrict__ b2,
    float* __restrict__ out) {
  __shared__ float sW1[8 * 32], sW2[32 * 16];
  __shared__ float sb1[32], sg[32], sbb[32], sb2[16];
  __shared__ float sx[16 * 8];     // reduced features per row
  __shared__ float sh[16 * 32];    // post-GELU hidden per row
  __shared__ float stmp[256];
  int t = threadIdx.x;
  sW1[t] = W1[t];
  sW2[t] = W2[t];
  sW2[t + 256] = W2[t + 256];
  if (t < 32) { sb1[t] = b1[t]; sg[t] = ln_g[t]; sbb[t] = ln_b[t]; }
  if (t < 16) sb2[t] = b2[t];

  int i0 = blockIdx.x * 16;

  // ---- reduce partial[SLICES][N][8] over slices ----
  {
    int r = t >> 4;          // row 0..15
    int q = (t >> 3) & 1;    // slice-half
    int f = t & 7;           // feature
    float s = 0.f;
    if (SLICES == 1) {
      if (q == 0) s = X[(size_t)(i0 + r) * 8 + f];
    } else {
      const float* src = X + ((size_t)(q * (SLICES / 2)) * N + (i0 + r)) * 8 + f;
#pragma unroll
      for (int k = 0; k < SLICES / 2; k++) s += src[(size_t)k * N * 8];
    }
    stmp[t] = s;
    __syncthreads();
    if (q == 0) sx[r * 8 + f] = stmp[t] + stmp[t + 8];
  }
  __syncthreads();

  // ---- MLP: 16 threads per row ----
  {
    int r = t >> 4;          // row 0..15 (4 rows per wave, 16-lane groups)
    int u = t & 15;
    const float diag[8] = {0.f, 0.f, 1.f, 1.f, 1.f, 0.f, 0.f, 0.f};
    const float inv_nm1 = 1.0f / (float)(N - 1);
    float x[8];
#pragma unroll
    for (int k = 0; k < 8; k++) x[k] = (sx[r * 8 + k] - diag[k]) * inv_nm1;

    int o0 = u * 2, o1 = o0 + 1;
    float h0 = sb1[o0], h1 = sb1[o1];
#pragma unroll
    for (int k = 0; k < 8; k++) {
      h0 += x[k] * sW1[k * 32 + o0];
      h1 += x[k] * sW1[k * 32 + o1];
    }

    // LayerNorm stats across the row's 32 hidden units (16-lane shfl groups)
    float sum = h0 + h1;
#pragma unroll
    for (int m = 1; m < 16; m <<= 1) sum += __shfl_xor(sum, m);
    float mu = sum * (1.0f / 32.0f);
    float d0 = h0 - mu, d1 = h1 - mu;
    float vs = d0 * d0 + d1 * d1;
#pragma unroll
    for (int m = 1; m < 16; m <<= 1) vs += __shfl_xor(vs, m);
    float inv = rsqrtf(vs * (1.0f / 32.0f) + 1e-5f);

    float hn0 = d0 * inv * sg[o0] + sbb[o0];
    float hn1 = d1 * inv * sg[o1] + sbb[o1];
    float g0 = 0.5f * hn0 * (1.0f + erff(hn0 * 0.70710678118654752f));
    float g1 = 0.5f * hn1 * (1.0f + erff(hn1 * 0.70710678118654752f));
    sh[r * 32 + o0] = g0;
    sh[r * 32 + o1] = g1;
    __syncthreads();

    // W2: each thread computes out[row][u]
    float a = sb2[u];
#pragma unroll
    for (int k = 0; k < 32; k++) a += sh[r * 32 + k] * sW2[k * 16 + u];
    out[(size_t)(i0 + r) * 16 + u] = a;
  }
}

extern "C" void kernel_launch(void* const* d_in, const int* in_sizes, int n_in,
                              void* d_out, int out_size, void* d_ws, size_t ws_size,
                              hipStream_t stream) {
  const float* p    = (const float*)d_in[0];
  const float* W1   = (const float*)d_in[1];
  const float* b1   = (const float*)d_in[2];
  const float* ln_g = (const float*)d_in[3];
  const float* ln_b = (const float*)d_in[4];
  const float* W2   = (const float*)d_in[5];
  const float* b2   = (const float*)d_in[6];
  float* out = (float*)d_out;
  float* ws  = (float*)d_ws;

  const size_t need_partial = (size_t)NJ * N * 8 * sizeof(float);  // 4 MB
  dim3 grid(N / IB, NJ);
  if (ws_size >= need_partial) {
    // split-K with private partial buffers; no atomics, no memset needed
    pairwise_kernel<true><<<grid, 256, 0, stream>>>(p, ws);
    mlp_kernel<NJ><<<N / 16, 256, 0, stream>>>(ws, W1, b1, ln_g, ln_b, W2, b2, out);
  } else {
    // fallback: atomic accumulation into X[N][8]
    hipMemsetAsync(ws, 0, (size_t)N * 8 * sizeof(float), stream);
    pairwise_kernel<false><<<grid, 256, 0, stream>>>(p, ws);
    mlp_kernel<1><<<N / 16, 256, 0, stream>>>(ws, W1, b1, ln_g, ln_b, W2, b2, out);
  }
}

// Round 7
// 82.082 us; speedup vs baseline: 1.2956x; 1.0131x over previous
//
#include <hip/hip_runtime.h>
#include <math.h>

#define N       4096
#define NPARAM  15
#define NJ      32          // j-slices (partial-sum path)
#define IB      64          // i-rows per pairwise block (one per lane)
#define JPB     (N / NJ)    // 128 j's per block
#define JPW     (JPB / 4)   // 32 j's per wave

typedef float f32x2 __attribute__((ext_vector_type(2)));

static __device__ __forceinline__ f32x2 abs2(f32x2 v) {
  return f32x2{fabsf(v.x), fabsf(v.y)};
}

// Derived per-point params (rescaled so the O(n^2) loop is minimal):
//   o0 = t, o1 = ra, o2 = dec, o3 = psi
//   o4 = mc/30                        (mass_sim = rcp(1+|d o4|))
//   o5 = 220*0.01*log2(e)/msum       (freq_ov  = exp2(-|d o5|))
//   o6 = log2(dist)                   (dist_rat = exp2(-|d o6|), exact)
__device__ __forceinline__ void derive_params(const float* __restrict__ r, float* o) {
  float m1 = fmaf(r[0], 95.0f, 5.0f);
  float m2 = fmaf(r[1], 95.0f, 5.0f);
  float msum = m1 + m2;
  float mc30 = __builtin_amdgcn_exp2f(
      0.6f * __builtin_amdgcn_logf(m1 * m2)
      - 0.2f * __builtin_amdgcn_logf(msum)
      - 4.906890595608519f);
  o[0] = r[5];
  o[1] = r[3];
  o[2] = r[4];
  o[3] = r[7];
  o[4] = mc30;
  o[5] = 3.1739290899556993f * __builtin_amdgcn_rcpf(msum);
  o[6] = __builtin_amdgcn_logf(fmaf(r[2], 2950.0f, 50.0f));
  o[7] = 0.0f;
}

// Block: 64 i's (one per lane), 4 waves split 128 j's (32 each; 2 j's per
// iteration via packed-f32 math), LDS-reduce, then one coalesced store of
// 64x8 partials to out[jb][i][8] (PARTIAL) or atomicAdd (fallback).
// LDS j-layout is pair-SoA: float4 = (param_a[j0], param_a[j1], param_b[j0], param_b[j1]).
template <bool PARTIAL>
__global__ __launch_bounds__(256, 8) void pairwise_kernel(
    const float* __restrict__ p, float* __restrict__ out) {
  __shared__ float4 sAB[JPB / 2];   // (t, ra)    pairs
  __shared__ float4 sCD[JPB / 2];   // (dec, psi) pairs
  __shared__ float4 sEF[JPB / 2];   // (mc', f')  pairs
  __shared__ float2 sG[JPB / 2];    // (log2 d)   pairs
  __shared__ float sacc[4 * IB * 8];
  int t    = threadIdx.x;
  int ib   = blockIdx.x;
  int jb   = blockIdx.y;
  int w    = t >> 6;
  int lane = t & 63;
  int i    = ib * IB + lane;

  // stage this block's 128 j-points (threads 0..127 derive one each)
  if (t < JPB) {
    int j = jb * JPB + t;
    float o[8];
    derive_params(p + (size_t)j * NPARAM, o);
    int h = t >> 1, l = t & 1;
    ((float*)sAB)[h * 4 + l]     = o[0];
    ((float*)sAB)[h * 4 + 2 + l] = o[1];
    ((float*)sCD)[h * 4 + l]     = o[2];
    ((float*)sCD)[h * 4 + 2 + l] = o[3];
    ((float*)sEF)[h * 4 + l]     = o[4];
    ((float*)sEF)[h * 4 + 2 + l] = o[5];
    ((float*)sG)[h * 2 + l]      = o[6];
  }

  // my i-point
  float pi[8];
  derive_params(p + (size_t)i * NPARAM, pi);
  float ti = pi[0], rai = pi[1], deci = pi[2], psii = pi[3];
  float mci = pi[4], fi = pi[5], di = pi[6];

  __syncthreads();

  f32x2 a_dt = {0.f, 0.f}, a_sky = {0.f, 0.f}, a_ms = {0.f, 0.f},
        a_fo = {0.f, 0.f}, a_dr = {0.f, 0.f}, a_ps = {0.f, 0.f},
        a_ra = {0.f, 0.f}, a_dc = {0.f, 0.f};

  // wave w handles j-pairs [w*16, w*16+16); LDS reads are wave-uniform broadcasts
  int qbase = w * (JPW / 2);
#pragma unroll
  for (int q = 0; q < JPW / 2; q++) {
    float4 ab = sAB[qbase + q];
    float4 cd = sCD[qbase + q];
    float4 ef = sEF[qbase + q];
    float2 g  = sG[qbase + q];
    f32x2 tj  = {ab.x, ab.y}, raj = {ab.z, ab.w};
    f32x2 dcj = {cd.x, cd.y}, psj = {cd.z, cd.w};
    f32x2 mcj = {ef.x, ef.y}, fj  = {ef.z, ef.w};
    f32x2 dj  = {g.x, g.y};

    f32x2 dra  = rai - raj;
    f32x2 ddec = deci - dcj;
    a_dt += abs2(ti - tj);
    a_ps += abs2(psii - psj);
    a_ra += abs2(dra);
    a_dc += abs2(ddec);
    f32x2 ss = dra * dra + ddec * ddec;
    a_sky += f32x2{__builtin_amdgcn_sqrtf(ss.x), __builtin_amdgcn_sqrtf(ss.y)};
    f32x2 u = 1.0f + abs2(mci - mcj);
    a_ms += f32x2{__builtin_amdgcn_rcpf(u.x), __builtin_amdgcn_rcpf(u.y)};
    f32x2 e1 = abs2(fi - fj);
    a_fo += f32x2{__builtin_amdgcn_exp2f(-e1.x), __builtin_amdgcn_exp2f(-e1.y)};
    f32x2 e2 = abs2(di - dj);
    a_dr += f32x2{__builtin_amdgcn_exp2f(-e2.x), __builtin_amdgcn_exp2f(-e2.y)};
  }

  float s0 = a_dt.x + a_dt.y;
  float s1 = a_sky.x + a_sky.y;
  float s2 = a_ms.x + a_ms.y;
  float s3 = a_fo.x + a_fo.y;
  float s4 = a_dr.x + a_dr.y;
  float s5 = a_ps.x + a_ps.y;
  float s6 = a_ra.x + a_ra.y;
  float s7 = a_dc.x + a_dc.y;

  // per-wave partials -> LDS
  float4* d = (float4*)(sacc + ((size_t)w * IB + lane) * 8);
  d[0] = make_float4(s0, s1, s2, s3);
  d[1] = make_float4(s4, s5, s6, s7);
  __syncthreads();

  // 4-way reduce + store: 512 (i,feat) values by 256 threads, coalesced
#pragma unroll
  for (int k = 0; k < 2; k++) {
    int pidx = t + k * 256;
    float v = sacc[pidx] + sacc[512 + pidx] + sacc[1024 + pidx] + sacc[1536 + pidx];
    if (PARTIAL) {
      out[((size_t)jb * N + (size_t)ib * IB) * 8 + pidx] = v;
    } else {
      atomicAdd(&out[((size_t)ib * IB) * 8 + pidx], v);
    }
  }
}

// Fused SLICES-way reduce + tiny MLP. 16 rows/block; reduction by 2 threads x 8
// feats per row; MLP by 16 threads per row (2 hidden units each, shfl LN).
template <int SLICES>
__global__ __launch_bounds__(256) void mlp_kernel(
    const float* __restrict__ X,
    const float* __restrict__ W1, const float* __restrict__ b1,
    const float* __restrict__ ln_g, const float* __restrict__ ln_b,
    const float* __restrict__ W2, const float* __restrict__ b2,
    float* __restrict__ out) {
  __shared__ float sW1[8 * 32], sW2[32 * 16];
  __shared__ float sb1[32], sg[32], sbb[32], sb2[16];
  __shared__ float sx[16 * 8];
  __shared__ float sh[16 * 32];
  __shared__ float stmp[256];
  int t = threadIdx.x;
  sW1[t] = W1[t];
  sW2[t] = W2[t];
  sW2[t + 256] = W2[t + 256];
  if (t < 32) { sb1[t] = b1[t]; sg[t] = ln_g[t]; sbb[t] = ln_b[t]; }
  if (t < 16) sb2[t] = b2[t];

  int i0 = blockIdx.x * 16;

  // ---- reduce partial[SLICES][N][8] over slices ----
  {
    int r = t >> 4;          // row 0..15
    int q = (t >> 3) & 1;    // slice-half
    int f = t & 7;           // feature
    float s = 0.f;
    if (SLICES == 1) {
      if (q == 0) s = X[(size_t)(i0 + r) * 8 + f];
    } else {
      const float* src = X + ((size_t)(q * (SLICES / 2)) * N + (i0 + r)) * 8 + f;
#pragma unroll
      for (int k = 0; k < SLICES / 2; k++) s += src[(size_t)k * N * 8];
    }
    stmp[t] = s;
    __syncthreads();
    if (q == 0) sx[r * 8 + f] = stmp[t] + stmp[t + 8];
  }
  __syncthreads();

  // ---- MLP: 16 threads per row ----
  {
    int r = t >> 4;
    int u = t & 15;
    const float diag[8] = {0.f, 0.f, 1.f, 1.f, 1.f, 0.f, 0.f, 0.f};
    const float inv_nm1 = 1.0f / (float)(N - 1);
    float x[8];
#pragma unroll
    for (int k = 0; k < 8; k++) x[k] = (sx[r * 8 + k] - diag[k]) * inv_nm1;

    int o0 = u * 2, o1 = o0 + 1;
    float h0 = sb1[o0], h1 = sb1[o1];
#pragma unroll
    for (int k = 0; k < 8; k++) {
      h0 += x[k] * sW1[k * 32 + o0];
      h1 += x[k] * sW1[k * 32 + o1];
    }

    float sum = h0 + h1;
#pragma unroll
    for (int m = 1; m < 16; m <<= 1) sum += __shfl_xor(sum, m);
    float mu = sum * (1.0f / 32.0f);
    float d0 = h0 - mu, d1 = h1 - mu;
    float vs = d0 * d0 + d1 * d1;
#pragma unroll
    for (int m = 1; m < 16; m <<= 1) vs += __shfl_xor(vs, m);
    float inv = rsqrtf(vs * (1.0f / 32.0f) + 1e-5f);

    float hn0 = d0 * inv * sg[o0] + sbb[o0];
    float hn1 = d1 * inv * sg[o1] + sbb[o1];
    float g0 = 0.5f * hn0 * (1.0f + erff(hn0 * 0.70710678118654752f));
    float g1 = 0.5f * hn1 * (1.0f + erff(hn1 * 0.70710678118654752f));
    sh[r * 32 + o0] = g0;
    sh[r * 32 + o1] = g1;
    __syncthreads();

    float a = sb2[u];
#pragma unroll
    for (int k = 0; k < 32; k++) a += sh[r * 32 + k] * sW2[k * 16 + u];
    out[(size_t)(i0 + r) * 16 + u] = a;
  }
}

extern "C" void kernel_launch(void* const* d_in, const int* in_sizes, int n_in,
                              void* d_out, int out_size, void* d_ws, size_t ws_size,
                              hipStream_t stream) {
  const float* p    = (const float*)d_in[0];
  const float* W1   = (const float*)d_in[1];
  const float* b1   = (const float*)d_in[2];
  const float* ln_g = (const float*)d_in[3];
  const float* ln_b = (const float*)d_in[4];
  const float* W2   = (const float*)d_in[5];
  const float* b2   = (const float*)d_in[6];
  float* out = (float*)d_out;
  float* ws  = (float*)d_ws;

  const size_t need_partial = (size_t)NJ * N * 8 * sizeof(float);  // 4 MB
  dim3 grid(N / IB, NJ);
  if (ws_size >= need_partial) {
    pairwise_kernel<true><<<grid, 256, 0, stream>>>(p, ws);
    mlp_kernel<NJ><<<N / 16, 256, 0, stream>>>(ws, W1, b1, ln_g, ln_b, W2, b2, out);
  } else {
    hipMemsetAsync(ws, 0, (size_t)N * 8 * sizeof(float), stream);
    pairwise_kernel<false><<<grid, 256, 0, stream>>>(p, ws);
    mlp_kernel<1><<<N / 16, 256, 0, stream>>>(ws, W1, b1, ln_g, ln_b, W2, b2, out);
  }
}